// Round 2
// baseline (1091.255 us; speedup 1.0000x reference)
//
#include <hip/hip_runtime.h>

#define NA 50000
#define NP 1600000
#define NT_PAIR (NP / 128)      // 12500 pair tiles of 128
#define PAIR_BLOCKS 1024

// ws layout (bytes)
#define WS_X     0               // x: NA*128 f32 = 25,600,000
#define WS_W1T   25600000        // 128*40 bf16  = 10,240
#define WS_W2T   25610240        // 128*136 bf16 = 34,816
#define WS_WINT  25645056
#define WS_WO1T  25679872
#define WS_WO2T  25714688

typedef __attribute__((ext_vector_type(4))) float f32x4;
typedef __attribute__((ext_vector_type(8))) short short8;

#define MFMA(a, b, c) __builtin_amdgcn_mfma_f32_16x16x32_bf16((a), (b), (c), 0, 0, 0)

__device__ __forceinline__ unsigned short f2bf(float f) {
    unsigned int u = __float_as_uint(f);
    u += 0x7FFFu + ((u >> 16) & 1u);     // round-to-nearest-even
    return (unsigned short)(u >> 16);
}

__device__ __forceinline__ float bf2f(unsigned short h) {
    return __uint_as_float(((unsigned int)h) << 16);
}

// shifted softplus: softplus(z) - ln2, numerically stable
__device__ __forceinline__ float ssp_f(float z) {
    float az = fabsf(z);
    float e  = __expf(-az);
    float l  = __logf(1.0f + e);
    return fmaxf(z, 0.0f) + l - 0.69314718056f;
}

// One 128x128-output register tile per block: 8 waves, each wave = 32 rows x 64 cols
// A stored [m][k] (LDA halfwords), B stored transposed [n][k] (LDB halfwords).
// A-frag: row = m0+(lane&15), k = ks*32 + (lane>>4)*8 + i  (contiguous -> ds_read_b128)
// B-frag: col = nc0+nt*16+(lane&15), same k slice
// C/D: col = lane&15 (+tile), row = (lane>>4)*4 + i  [verified layout, m89/m91]
template <int LDA, int LDB, int KS, bool SPLIT>
__device__ __forceinline__ void gemm_t(const unsigned short* A, const unsigned short* Al,
                                       const unsigned short* B, int m0, int nc0,
                                       int lr, int lg, f32x4 (&acc)[2][4]) {
#pragma unroll
    for (int ks = 0; ks < KS; ++ks) {
        const int ko = ks * 32 + lg * 8;
        short8 a0 = *(const short8*)(A + (m0 + lr) * LDA + ko);
        short8 a1 = *(const short8*)(A + (m0 + 16 + lr) * LDA + ko);
        short8 a0l, a1l;
        if constexpr (SPLIT) {
            a0l = *(const short8*)(Al + (m0 + lr) * LDA + ko);
            a1l = *(const short8*)(Al + (m0 + 16 + lr) * LDA + ko);
        }
#pragma unroll
        for (int nt = 0; nt < 4; ++nt) {
            short8 b = *(const short8*)(B + (nc0 + nt * 16 + lr) * LDB + ko);
            acc[0][nt] = MFMA(a0, b, acc[0][nt]);
            acc[1][nt] = MFMA(a1, b, acc[1][nt]);
            if constexpr (SPLIT) {
                acc[0][nt] = MFMA(a0l, b, acc[0][nt]);
                acc[1][nt] = MFMA(a1l, b, acc[1][nt]);
            }
        }
    }
}

// ---------------- prep: transpose weights to bf16 [n][k] padded layouts in ws ----------
__global__ void prep_kernel(const float* __restrict__ Wf1, const float* __restrict__ Wf2,
                            const float* __restrict__ Win, const float* __restrict__ Wo1,
                            const float* __restrict__ Wo2, unsigned short* __restrict__ w1t,
                            unsigned short* __restrict__ w2t, unsigned short* __restrict__ wint,
                            unsigned short* __restrict__ wo1t, unsigned short* __restrict__ wo2t) {
    const int n = blockIdx.x;    // 0..127 output col
    const int k = threadIdx.x;   // 0..255
    const int m = blockIdx.y;
    if (m == 0) {
        if (k < 40) w1t[n * 40 + k] = (k < 20) ? f2bf(Wf1[k * 128 + n]) : (unsigned short)0;
    } else {
        const float* src = (m == 1) ? Wf2 : (m == 2) ? Win : (m == 3) ? Wo1 : Wo2;
        unsigned short* dst = (m == 1) ? w2t : (m == 2) ? wint : (m == 3) ? wo1t : wo2t;
        if (k < 136) dst[n * 136 + k] = (k < 128) ? f2bf(src[k * 128 + n]) : (unsigned short)0;
    }
}

// ---------------- xproj: x = emb @ W_in  (bf16 split-A MFMA, fp32 out) -----------------
__global__ __launch_bounds__(512, 2) void xproj_kernel(const float* __restrict__ emb,
                                                       const unsigned short* __restrict__ wint,
                                                       float* __restrict__ x) {
    __shared__ __align__(16) unsigned short sAh[128 * 136];
    __shared__ __align__(16) unsigned short sAl[128 * 136];
    __shared__ __align__(16) unsigned short sW[128 * 136];
    const int tid = threadIdx.x;
    const int r0 = blockIdx.x * 128;
#pragma unroll
    for (int it = 0; it < 32; ++it) {
        int idx = it * 512 + tid;
        int row = idx >> 7, col = idx & 127;
        int r = r0 + row;
        float v = (r < NA) ? emb[(size_t)r * 128 + col] : 0.0f;
        unsigned short hi = f2bf(v);
        unsigned short lo = f2bf(v - bf2f(hi));
        sAh[row * 136 + col] = hi;
        sAl[row * 136 + col] = lo;
    }
    {
        const unsigned int* s = (const unsigned int*)wint;
        unsigned int* d = (unsigned int*)sW;
        for (int i = tid; i < 128 * 136 / 2; i += 512) d[i] = s[i];
    }
    __syncthreads();
    const int lane = tid & 63, wave = tid >> 6;
    const int lr = lane & 15, lg = lane >> 4;
    const int m0 = (wave & 3) * 32, nc0 = (wave >> 2) * 64;
    f32x4 acc[2][4] = {};
    gemm_t<136, 136, 4, true>(sAh, sAl, sW, m0, nc0, lr, lg, acc);
#pragma unroll
    for (int mt = 0; mt < 2; ++mt)
#pragma unroll
        for (int i = 0; i < 4; ++i) {
            int rl = m0 + mt * 16 + lg * 4 + i;
            int r = r0 + rl;
            if (r < NA) {
#pragma unroll
                for (int nt = 0; nt < 4; ++nt) {
                    int col = nc0 + nt * 16 + lr;
                    x[(size_t)r * 128 + col] = acc[mt][nt][i];
                }
            }
        }
}

// ---------------- pair kernel: fused filter-net + gather + scatter-add -----------------
__global__ __launch_bounds__(512, 2) void pair_kernel(
        const float* __restrict__ fij, const float* __restrict__ fcut,
        const int* __restrict__ idxI, const int* __restrict__ idxJ,
        const float* __restrict__ x, const unsigned short* __restrict__ w1t,
        const unsigned short* __restrict__ w2t, const float* __restrict__ bf1,
        const float* __restrict__ bf2, float* __restrict__ out) {
    __shared__ __align__(16) unsigned short sW1[128 * 40];
    __shared__ __align__(16) unsigned short sW2[128 * 136];
    __shared__ __align__(16) unsigned short sF[2][128 * 40];
    __shared__ __align__(16) unsigned short sH[128 * 136];
    __shared__ float sB1[128], sB2[128];
    __shared__ float sCut[2][128];
    __shared__ int sII[2][128], sJJ[2][128];

    const int tid = threadIdx.x;
    {   // stage weights (once per block), zero f_ij pads
        const unsigned int* s1 = (const unsigned int*)w1t;
        unsigned int* d1 = (unsigned int*)sW1;
        for (int i = tid; i < 128 * 40 / 2; i += 512) d1[i] = s1[i];
        const unsigned int* s2 = (const unsigned int*)w2t;
        unsigned int* d2 = (unsigned int*)sW2;
        for (int i = tid; i < 128 * 136 / 2; i += 512) d2[i] = s2[i];
        if (tid < 128) { sB1[tid] = bf1[tid]; sB2[tid] = bf2[tid]; }
        unsigned int* z = (unsigned int*)&sF[0][0];
        for (int i = tid; i < 2 * 128 * 40 / 2; i += 512) z[i] = 0;
    }
    const int lane = tid & 63, wave = tid >> 6;
    const int lr = lane & 15, lg = lane >> 4;
    const int m0 = (wave & 3) * 32, nc0 = (wave >> 2) * 64;

    int t = blockIdx.x;
    float pf[5];
    int pi = 0, pj = 0;
    float pc = 0.0f;
    auto pref = [&](int T) {
        const float* fp = fij + (size_t)T * 2560;
#pragma unroll
        for (int r = 0; r < 5; ++r) pf[r] = fp[r * 512 + tid];
        if (tid < 128) {
            pi = idxI[T * 128 + tid];
            pj = idxJ[T * 128 + tid];
            pc = fcut[T * 128 + tid];
        }
    };
    pref(t);
    int buf = 0;
    __syncthreads();

    for (; t < NT_PAIR;) {
        // write staged tile -> LDS (bf16, K padded to 32 with pre-zeroed pads)
#pragma unroll
        for (int r = 0; r < 5; ++r) {
            int idx = r * 512 + tid;
            int p = (int)(__umulhi((unsigned)idx, 0xCCCCCCCDu) >> 4);   // idx / 20
            int k = idx - p * 20;
            sF[buf][p * 40 + k] = f2bf(pf[r]);
        }
        if (tid < 128) { sII[buf][tid] = pi; sJJ[buf][tid] = pj; sCut[buf][tid] = pc; }
        int tn = t + PAIR_BLOCKS;
        if (tn < NT_PAIR) pref(tn);
        __syncthreads();   // sF[buf] ready; sH free (all waves past previous GEMM2)

        // GEMM1: h = f_ij @ W_f1  (K=32 incl. zero pad)
        f32x4 acc1[2][4] = {};
        gemm_t<40, 40, 1, false>(&sF[buf][0], nullptr, sW1, m0, nc0, lr, lg, acc1);

        // ssp(h + b1) -> sH (bf16)
#pragma unroll
        for (int mt = 0; mt < 2; ++mt)
#pragma unroll
            for (int nt = 0; nt < 4; ++nt) {
                int col = nc0 + nt * 16 + lr;
                float b1 = sB1[col];
#pragma unroll
                for (int i = 0; i < 4; ++i) {
                    int rl = m0 + mt * 16 + lg * 4 + i;
                    sH[rl * 136 + col] = f2bf(ssp_f(acc1[mt][nt][i] + b1));
                }
            }
        __syncthreads();   // sH ready

        // GEMM2: W_ij = h @ W_f2  (K=128)
        f32x4 acc2[2][4] = {};
        gemm_t<136, 136, 4, false>(sH, nullptr, sW2, m0, nc0, lr, lg, acc2);

        // epilogue: (+b2) * cutoff * x[idx_j]  -> atomicAdd out[idx_i]
#pragma unroll
        for (int mt = 0; mt < 2; ++mt) {
#pragma unroll
            for (int i = 0; i < 4; ++i) {
                int rl = m0 + mt * 16 + lg * 4 + i;
                int ii = sII[buf][rl];
                int jj = sJJ[buf][rl];
                float cc = sCut[buf][rl];
                const float* xr = x + (size_t)jj * 128;
                float* orow = out + (size_t)ii * 128;
#pragma unroll
                for (int nt = 0; nt < 4; ++nt) {
                    int col = nc0 + nt * 16 + lr;
                    float v = (acc2[mt][nt][i] + sB2[col]) * cc * xr[col];
                    unsafeAtomicAdd(&orow[col], v);
                }
            }
        }
        buf ^= 1;
        t = tn;
        // no barrier needed here: next iteration writes the other buffer only
    }
}

// ---------------- output MLP, in-place on d_out (split-A bf16 MFMA) --------------------
__global__ __launch_bounds__(512, 2) void mlp_kernel(const unsigned short* __restrict__ wo1t,
                                                     const unsigned short* __restrict__ wo2t,
                                                     const float* __restrict__ bo1,
                                                     const float* __restrict__ bo2,
                                                     float* __restrict__ out) {
    __shared__ __align__(16) unsigned short sAh[128 * 136];
    __shared__ __align__(16) unsigned short sAl[128 * 136];
    __shared__ __align__(16) unsigned short sW[128 * 136];
    __shared__ float sb1[128], sb2[128];
    const int tid = threadIdx.x;
    const int r0 = blockIdx.x * 128;
#pragma unroll
    for (int it = 0; it < 32; ++it) {
        int idx = it * 512 + tid;
        int row = idx >> 7, col = idx & 127;
        int r = r0 + row;
        float v = (r < NA) ? out[(size_t)r * 128 + col] : 0.0f;
        unsigned short hi = f2bf(v);
        unsigned short lo = f2bf(v - bf2f(hi));
        sAh[row * 136 + col] = hi;
        sAl[row * 136 + col] = lo;
    }
    {
        const unsigned int* s = (const unsigned int*)wo1t;
        unsigned int* d = (unsigned int*)sW;
        for (int i = tid; i < 128 * 136 / 2; i += 512) d[i] = s[i];
    }
    if (tid < 128) { sb1[tid] = bo1[tid]; sb2[tid] = bo2[tid]; }
    __syncthreads();
    const int lane = tid & 63, wave = tid >> 6;
    const int lr = lane & 15, lg = lane >> 4;
    const int m0 = (wave & 3) * 32, nc0 = (wave >> 2) * 64;

    f32x4 acc[2][4] = {};
    gemm_t<136, 136, 4, true>(sAh, sAl, sW, m0, nc0, lr, lg, acc);
    __syncthreads();   // all waves done reading sAh/sAl/sW

    // h = ssp(acc + b1) -> sAh (single bf16); restage sW <- Wo2T
#pragma unroll
    for (int mt = 0; mt < 2; ++mt)
#pragma unroll
        for (int nt = 0; nt < 4; ++nt) {
            int col = nc0 + nt * 16 + lr;
            float b1 = sb1[col];
#pragma unroll
            for (int i = 0; i < 4; ++i) {
                int rl = m0 + mt * 16 + lg * 4 + i;
                sAh[rl * 136 + col] = f2bf(ssp_f(acc[mt][nt][i] + b1));
            }
        }
    {
        const unsigned int* s = (const unsigned int*)wo2t;
        unsigned int* d = (unsigned int*)sW;
        for (int i = tid; i < 128 * 136 / 2; i += 512) d[i] = s[i];
    }
    __syncthreads();

    f32x4 acc2[2][4] = {};
    gemm_t<136, 136, 4, false>(sAh, nullptr, sW, m0, nc0, lr, lg, acc2);
#pragma unroll
    for (int mt = 0; mt < 2; ++mt)
#pragma unroll
        for (int i = 0; i < 4; ++i) {
            int rl = m0 + mt * 16 + lg * 4 + i;
            int r = r0 + rl;
            if (r < NA) {
#pragma unroll
                for (int nt = 0; nt < 4; ++nt) {
                    int col = nc0 + nt * 16 + lr;
                    out[(size_t)r * 128 + col] = acc2[mt][nt][i] + sb2[col];
                }
            }
        }
}

extern "C" void kernel_launch(void* const* d_in, const int* in_sizes, int n_in,
                              void* d_out, int out_size, void* d_ws, size_t ws_size,
                              hipStream_t stream) {
    const float* emb  = (const float*)d_in[0];
    const int*   pidx = (const int*)d_in[1];
    const float* fij  = (const float*)d_in[2];
    const float* fcut = (const float*)d_in[3];
    const float* Win  = (const float*)d_in[4];
    const float* Wf1  = (const float*)d_in[5];
    const float* bf1  = (const float*)d_in[6];
    const float* Wf2  = (const float*)d_in[7];
    const float* bf2  = (const float*)d_in[8];
    const float* Wo1  = (const float*)d_in[9];
    const float* bo1  = (const float*)d_in[10];
    const float* Wo2  = (const float*)d_in[11];
    const float* bo2  = (const float*)d_in[12];
    float* out = (float*)d_out;
    char* ws = (char*)d_ws;

    float* x = (float*)(ws + WS_X);
    unsigned short* w1t  = (unsigned short*)(ws + WS_W1T);
    unsigned short* w2t  = (unsigned short*)(ws + WS_W2T);
    unsigned short* wint = (unsigned short*)(ws + WS_WINT);
    unsigned short* wo1t = (unsigned short*)(ws + WS_WO1T);
    unsigned short* wo2t = (unsigned short*)(ws + WS_WO2T);

    hipMemsetAsync(d_out, 0, (size_t)NA * 128 * sizeof(float), stream);
    prep_kernel<<<dim3(128, 5), 256, 0, stream>>>(Wf1, Wf2, Win, Wo1, Wo2,
                                                  w1t, w2t, wint, wo1t, wo2t);
    xproj_kernel<<<(NA + 127) / 128, 512, 0, stream>>>(emb, wint, x);
    pair_kernel<<<PAIR_BLOCKS, 512, 0, stream>>>(fij, fcut, pidx, pidx + NP, x,
                                                 w1t, w2t, bf1, bf2, out);
    mlp_kernel<<<(NA + 127) / 128, 512, 0, stream>>>(wo1t, wo2t, bo1, bo2, out);
}